// Round 1
// baseline (33.397 us; speedup 1.0000x reference)
//
#include <hip/hip_runtime.h>
#include <math.h>

namespace {

constexpr float kInvTau = 10.0f;      // 1 / 0.1
constexpr int   kBlock  = 256;
constexpr int   kGrid   = 2048;       // pass-1 blocks
constexpr float kNegBig = -1e30f;     // -inf surrogate (avoids NaN in merges)

// ---------- kernel A: per-type projection + sigmoid --------------------
__global__ void pc_kernel(const float* __restrict__ table,
                          const float* __restrict__ w,
                          const float* __restrict__ b,
                          const float* __restrict__ cl,
                          float2* __restrict__ pc, int T) {
    int t = blockIdx.x * blockDim.x + threadIdx.x;
    if (t >= T) return;
    const float4* row = reinterpret_cast<const float4*>(table) + (size_t)t * 4;
    const float4* wv  = reinterpret_cast<const float4*>(w);
    float4 r0 = row[0], r1 = row[1], r2 = row[2], r3 = row[3];
    float4 w0 = wv[0],  w1 = wv[1],  w2 = wv[2],  w3 = wv[3];
    float dot = r0.x*w0.x + r0.y*w0.y + r0.z*w0.z + r0.w*w0.w
              + r1.x*w1.x + r1.y*w1.y + r1.z*w1.z + r1.w*w1.w
              + r2.x*w2.x + r2.y*w2.y + r2.z*w2.z + r2.w*w2.w
              + r3.x*w3.x + r3.y*w3.y + r3.z*w3.z + r3.w*w3.w;
    float p = (dot + b[0]) * kInvTau;
    float c = 1.0f / (1.0f + __expf(-cl[t]));
    pc[t] = make_float2(p, c);
}

// merge two online-softmax states (m, s, t)
__device__ __forceinline__ void merge_state(float& m, float& s, float& t,
                                            float m2, float s2, float t2) {
    float nm = fmaxf(m, m2);
    float r1 = __expf(m  - nm);
    float r2 = __expf(m2 - nm);
    s = s * r1 + s2 * r2;
    t = t * r1 + t2 * r2;
    m = nm;
}

// wave(64) + block reduction of (m,s,t); result valid in thread 0
__device__ __forceinline__ void block_reduce(float& m, float& s, float& t) {
    #pragma unroll
    for (int off = 1; off < 64; off <<= 1) {
        float m2 = __shfl_xor(m, off);
        float s2 = __shfl_xor(s, off);
        float t2 = __shfl_xor(t, off);
        merge_state(m, s, t, m2, s2, t2);
    }
    __shared__ float sm[4], ss[4], st[4];
    int lane = threadIdx.x & 63;
    int wave = threadIdx.x >> 6;
    if (lane == 0) { sm[wave] = m; ss[wave] = s; st[wave] = t; }
    __syncthreads();
    if (threadIdx.x == 0) {
        int nw = blockDim.x >> 6;
        for (int i = 1; i < nw; ++i)
            merge_state(m, s, t, sm[i], ss[i], st[i]);
    }
}

// ---------- kernel B: streaming online softmax over the trace ----------
__global__ __launch_bounds__(kBlock)
void pass_kernel(const int* __restrict__ trace, int S,
                 const float2* __restrict__ pc,
                 float4* __restrict__ blk) {
    float m = kNegBig, s = 0.f, t = 0.f;
    int tid    = blockIdx.x * blockDim.x + threadIdx.x;
    int stride = gridDim.x * blockDim.x;

    const int4* trace4 = reinterpret_cast<const int4*>(trace);
    int S4 = S >> 2;
    for (int i = tid; i < S4; i += stride) {
        int4 v = trace4[i];
        float2 a0 = pc[v.x], a1 = pc[v.y], a2 = pc[v.z], a3 = pc[v.w];
        float lm = fmaxf(fmaxf(a0.x, a1.x), fmaxf(a2.x, a3.x));
        if (lm > m) {
            float r = __expf(m - lm);
            s *= r; t *= r; m = lm;
        }
        float e0 = __expf(a0.x - m);
        float e1 = __expf(a1.x - m);
        float e2 = __expf(a2.x - m);
        float e3 = __expf(a3.x - m);
        s += (e0 + e1) + (e2 + e3);
        t += (e0 * a0.y + e1 * a1.y) + (e2 * a2.y + e3 * a3.y);
    }
    // scalar tail (S not multiple of 4)
    for (int i = (S4 << 2) + tid; i < S; i += stride) {
        float2 a = pc[trace[i]];
        if (a.x > m) { float r = __expf(m - a.x); s *= r; t *= r; m = a.x; }
        float e = __expf(a.x - m);
        s += e; t += e * a.y;
    }

    block_reduce(m, s, t);
    if (threadIdx.x == 0) blk[blockIdx.x] = make_float4(m, s, t, 0.f);
}

// ---------- kernel C: finalize ------------------------------------------
__global__ void final_kernel(const float4* __restrict__ blk, int nblk,
                             const int* __restrict__ is_crash,
                             float* __restrict__ out) {
    float m = kNegBig, s = 0.f, t = 0.f;
    for (int i = threadIdx.x; i < nblk; i += blockDim.x) {
        float4 b = blk[i];
        merge_state(m, s, t, b.x, b.y, b.z);
    }
    block_reduce(m, s, t);
    if (threadIdx.x == 0) {
        float explained = (s > 0.f) ? (t / s) : 0.f;
        explained = fminf(fmaxf(explained, 0.f), 1.f);
        float contradiction = (is_crash[0] > 0)
            ? fmaxf(1.0f - explained, 0.f)
            : fmaxf(explained, 0.f);
        out[0] = contradiction;
    }
}

} // namespace

extern "C" void kernel_launch(void* const* d_in, const int* in_sizes, int n_in,
                              void* d_out, int out_size, void* d_ws, size_t ws_size,
                              hipStream_t stream) {
    const int*   trace = (const int*)  d_in[0];
    const int*   crash = (const int*)  d_in[1];
    const float* table = (const float*)d_in[2];
    const float* w     = (const float*)d_in[3];
    const float* b     = (const float*)d_in[4];
    const float* cl    = (const float*)d_in[5];
    float*       out   = (float*)d_out;

    const int S = in_sizes[0];
    const int T = in_sizes[5];

    // ws layout: [ float2 pc[T] | float4 blk[kGrid] ]
    float2* pc  = (float2*)d_ws;
    float4* blk = (float4*)((char*)d_ws + (size_t)T * sizeof(float2));

    int gridA = (T + kBlock - 1) / kBlock;
    pc_kernel<<<gridA, kBlock, 0, stream>>>(table, w, b, cl, pc, T);
    pass_kernel<<<kGrid, kBlock, 0, stream>>>(trace, S, pc, blk);
    final_kernel<<<1, kBlock, 0, stream>>>(blk, kGrid, crash, out);
}